// Round 1
// baseline (3600.232 us; speedup 1.0000x reference)
//
#include <hip/hip_runtime.h>

// ViT forward (3D patch embed + 12 encoder layers + final LN) on MI355X.
// Strategy R0: bf16 MFMA 16x16x32 everywhere, fp32 residual stream.
// Weights transpose-cast to bf16 [N][K] so GEMM stages A and B identically
// via global_load_lds (m97 structure). Flash-style fused attention.

#define MTOK 2464
#define NTOK 1232
#define NPAD 1248

typedef __attribute__((ext_vector_type(8))) short bf16x8;
typedef __attribute__((ext_vector_type(4))) short bf16x4;
typedef __attribute__((ext_vector_type(4))) float f32x4;

__device__ __forceinline__ short f2bf(float f) {
  union { float f; unsigned u; } v; v.f = f;
  unsigned r = v.u + 0x7FFFu + ((v.u >> 16) & 1u);
  return (short)(r >> 16);
}

__device__ __forceinline__ f32x4 mfma16(bf16x8 a, bf16x8 b, f32x4 c) {
  return __builtin_amdgcn_mfma_f32_16x16x32_bf16(a, b, c, 0, 0, 0);
}

// ---- weight transpose-cast: src fp32 [R][C] (batched over z) -> dst bf16 [C][R]
__global__ __launch_bounds__(256)
void transpose_cast_k(const float* __restrict__ src, short* __restrict__ dst,
                      int R, int C) {
  __shared__ float t[32][33];
  const size_t zoff = (size_t)blockIdx.z * R * C;
  const float* s = src + zoff;
  short* d = dst + zoff;
  const int tid = threadIdx.x;
  const int c0 = blockIdx.x * 32, r0 = blockIdx.y * 32;
  const int cc = tid & 31, rr = tid >> 5;
#pragma unroll
  for (int p = 0; p < 4; ++p)
    t[rr + p * 8][cc] = s[(size_t)(r0 + rr + p * 8) * C + c0 + cc];
  __syncthreads();
#pragma unroll
  for (int p = 0; p < 4; ++p)
    d[(size_t)(c0 + rr + p * 8) * R + r0 + cc] = f2bf(t[cc][rr + p * 8]);
}

// ---- plain cast (conv_w already [N][K]-major)
__global__ __launch_bounds__(256)
void cast_k(const float* __restrict__ src, short* __restrict__ dst, int n4) {
  int i = blockIdx.x * 256 + threadIdx.x;
  if (i >= n4) return;
  float4 f = ((const float4*)src)[i];
  bf16x4 o; o.x = f2bf(f.x); o.y = f2bf(f.y); o.z = f2bf(f.z); o.w = f2bf(f.w);
  ((bf16x4*)dst)[i] = o;
}

// ---- im2col: x fp32 [2][1][112][256][176] -> patches bf16 [2464][4096]
__global__ __launch_bounds__(256)
void im2col_k(const float* __restrict__ x, short* __restrict__ patches) {
  const int row = blockIdx.x;          // b*1232 + n
  const int tid = threadIdx.x;         // pz*16+py
  const int b = row >= NTOK;
  const int n = row - b * NTOK;
  const int dz = n / 176;
  const int r2 = n - dz * 176;
  const int dy = r2 / 11;
  const int dx = r2 - dy * 11;
  const int pz = tid >> 4, py = tid & 15;
  const float* src = x + (((size_t)(b * 112 + dz * 16 + pz) * 256) + dy * 16 + py) * 176 + dx * 16;
  short* dst = patches + (size_t)row * 4096 + pz * 256 + py * 16;
#pragma unroll
  for (int q = 0; q < 4; ++q) {
    float4 f = ((const float4*)src)[q];
    bf16x4 o; o.x = f2bf(f.x); o.y = f2bf(f.y); o.z = f2bf(f.z); o.w = f2bf(f.w);
    ((bf16x4*)dst)[q] = o;
  }
}

// ---- LayerNorm over E=768. BF16OUT: write y bf16, else fp32 (final).
template<bool BF16OUT>
__global__ __launch_bounds__(256)
void ln_k(const float* __restrict__ x, const float* __restrict__ sc,
          const float* __restrict__ bi, short* __restrict__ yb,
          float* __restrict__ yf) {
  const int row = blockIdx.x, tid = threadIdx.x;
  const float* xr = x + (size_t)row * 768;
  float v0 = xr[tid], v1 = xr[tid + 256], v2 = xr[tid + 512];
  float s1 = v0 + v1 + v2;
  float s2 = v0 * v0 + v1 * v1 + v2 * v2;
#pragma unroll
  for (int d = 1; d < 64; d <<= 1) { s1 += __shfl_xor(s1, d); s2 += __shfl_xor(s2, d); }
  __shared__ float sh[8];
  const int w = tid >> 6;
  if ((tid & 63) == 0) { sh[w] = s1; sh[4 + w] = s2; }
  __syncthreads();
  s1 = sh[0] + sh[1] + sh[2] + sh[3];
  s2 = sh[4] + sh[5] + sh[6] + sh[7];
  const float mean = s1 * (1.f / 768.f);
  const float var = s2 * (1.f / 768.f) - mean * mean;
  const float rs = rsqrtf(var + 1e-5f);
  float vv[3] = {v0, v1, v2};
#pragma unroll
  for (int i = 0; i < 3; ++i) {
    const int c = tid + i * 256;
    const float o = (vv[i] - mean) * rs * sc[c] + bi[c];
    if (BF16OUT) yb[(size_t)row * 768 + c] = f2bf(o);
    else         yf[(size_t)row * 768 + c] = o;
  }
}

// ---- GEMM: A bf16 [M][K], B bf16 [N][K] (i.e. B^T layout), 128x128x32 tile.
enum { EPI_CONV = 0, EPI_QKV = 1, EPI_ADDTOK = 2, EPI_GELU = 3 };

template<int EPI>
__global__ __launch_bounds__(256, 3)
void gemm_bt(const short* __restrict__ A, const short* __restrict__ B,
             const float* __restrict__ bias, int M, int N, int K,
             float* __restrict__ tokf, const float* __restrict__ pos,
             short* __restrict__ o0, short* __restrict__ o1,
             short* __restrict__ o2) {
  __shared__ short As[128 * 32];
  __shared__ short Bs[128 * 32];
  const int tid = threadIdx.x;
  const int l = tid & 63, w = tid >> 6;
  const int lhi = l >> 4, llo = l & 15;
  const int wr = w >> 1, wc = w & 1;
  const int m0 = blockIdx.x * 128, n0 = blockIdx.y * 128;

  const f32x4 zf = {0.f, 0.f, 0.f, 0.f};
  f32x4 acc[4][4];
#pragma unroll
  for (int r = 0; r < 4; ++r)
#pragma unroll
    for (int c = 0; c < 4; ++c) acc[r][c] = zf;

  for (int k0 = 0; k0 < K; k0 += 32) {
#pragma unroll
    for (int p = 0; p < 2; ++p) {
      const int f = p * 256 + tid;
      const int row = f >> 2, kc = f & 3;
      int gr = m0 + row; gr = gr < M ? gr : M - 1;
      const short* gp = A + (size_t)gr * K + k0 + kc * 8;
      __builtin_amdgcn_global_load_lds(
          (const __attribute__((address_space(1))) unsigned*)gp,
          (__attribute__((address_space(3))) unsigned*)(As + (p * 256 + w * 64) * 8),
          16, 0, 0);
    }
#pragma unroll
    for (int p = 0; p < 2; ++p) {
      const int f = p * 256 + tid;
      const int row = f >> 2, kc = f & 3;
      const short* gp = B + (size_t)(n0 + row) * K + k0 + kc * 8;
      __builtin_amdgcn_global_load_lds(
          (const __attribute__((address_space(1))) unsigned*)gp,
          (__attribute__((address_space(3))) unsigned*)(Bs + (p * 256 + w * 64) * 8),
          16, 0, 0);
    }
    __syncthreads();
    bf16x8 af[4], bfr[4];
#pragma unroll
    for (int r = 0; r < 4; ++r)
      af[r] = *(const bf16x8*)(As + (wr * 64 + r * 16 + llo) * 32 + lhi * 8);
#pragma unroll
    for (int c = 0; c < 4; ++c)
      bfr[c] = *(const bf16x8*)(Bs + (wc * 64 + c * 16 + llo) * 32 + lhi * 8);
#pragma unroll
    for (int r = 0; r < 4; ++r)
#pragma unroll
      for (int c = 0; c < 4; ++c)
        acc[r][c] = mfma16(af[r], bfr[c], acc[r][c]);
    __syncthreads();
  }

#pragma unroll
  for (int c = 0; c < 4; ++c) {
    const int gcol = n0 + wc * 64 + c * 16 + llo;
    const float bv = bias[gcol];
    int which = 0, hc = 0;
    if (EPI == EPI_QKV) { which = gcol / 768; hc = gcol - which * 768; }
#pragma unroll
    for (int r = 0; r < 4; ++r) {
      const int rb = m0 + wr * 64 + r * 16 + lhi * 4;
#pragma unroll
      for (int e = 0; e < 4; ++e) {
        const int grow = rb + e;
        if (grow >= M) continue;
        const float v = acc[r][c][e] + bv;
        if (EPI == EPI_CONV) {
          const int n = grow < NTOK ? grow : grow - NTOK;
          tokf[(size_t)grow * 768 + gcol] = v + pos[(size_t)n * 768 + gcol];
        } else if (EPI == EPI_ADDTOK) {
          tokf[(size_t)grow * 768 + gcol] += v;
        } else if (EPI == EPI_GELU) {
          o0[(size_t)grow * 3072 + gcol] = f2bf(0.5f * v * (1.f + erff(v * 0.70710678118f)));
        } else {  // QKV scatter to [B,H,NPAD,64]
          const int b = grow >= NTOK;
          const int n = grow - b * NTOK;
          short* dst = which == 0 ? o0 : (which == 1 ? o1 : o2);
          dst[((size_t)(b * 12 + (hc >> 6)) * NPAD + n) * 64 + (hc & 63)] = f2bf(v);
        }
      }
    }
  }
}

// ---- fused flash attention: grid (20 qtiles, 24 bh); 4 waves x 16 q-rows.
__global__ __launch_bounds__(256, 3)
void attn_k(const short* __restrict__ qb, const short* __restrict__ kb,
            const short* __restrict__ vb, short* __restrict__ ob) {
  const int tid = threadIdx.x;
  const int l = tid & 63, w = tid >> 6;
  const int lhi = l >> 4, llo = l & 15;
  const int qt = blockIdx.x, bh = blockIdx.y;
  const int b = bh / 12, h = bh - b * 12;
  const size_t base = (size_t)bh * NPAD * 64;
  const short* qp = qb + base;
  const short* kp = kb + base;
  const short* vp = vb + base;

  __shared__ short Ks[32 * 72];   // [kv][64] pad->72
  __shared__ short Vs[64 * 40];   // [d][kv 32] pad->40 (transposed)
  __shared__ short Ps[4][16 * 40];

  const int q0 = qt * 64 + w * 16;
  bf16x8 qfr[2];
  {
    int r = q0 + llo; if (r > NTOK - 1) r = NTOK - 1;
    qfr[0] = *(const bf16x8*)(qp + (size_t)r * 64 + lhi * 8);
    qfr[1] = *(const bf16x8*)(qp + (size_t)r * 64 + 32 + lhi * 8);
  }
  const f32x4 zf = {0.f, 0.f, 0.f, 0.f};
  float mrun[4], lrun[4], corr[4];
  f32x4 oacc[4];
#pragma unroll
  for (int e = 0; e < 4; ++e) { mrun[e] = -1e30f; lrun[e] = 0.f; }
#pragma unroll
  for (int d = 0; d < 4; ++d) oacc[d] = zf;

  for (int t = 0; t < 39; ++t) {
    __syncthreads();
    if (tid < 128) {  // K tile: [32][64] -> Ks
      const int kvr = tid >> 2, dc2 = tid & 3;
      const short* sp = kp + (size_t)(t * 32 + kvr) * 64 + dc2 * 16;
      *(bf16x8*)(Ks + kvr * 72 + dc2 * 16) = *(const bf16x8*)sp;
      *(bf16x8*)(Ks + kvr * 72 + dc2 * 16 + 8) = *(const bf16x8*)(sp + 8);
    } else {          // V tile transposed: 4x4 micro-transpose
      const int t2 = tid - 128;
      const int dv = t2 & 15, kvb = t2 >> 4;
      const short* sp = vp + (size_t)(t * 32 + kvb * 4) * 64 + dv * 4;
      bf16x4 a0 = *(const bf16x4*)(sp);
      bf16x4 a1 = *(const bf16x4*)(sp + 64);
      bf16x4 a2 = *(const bf16x4*)(sp + 128);
      bf16x4 a3 = *(const bf16x4*)(sp + 192);
      short* db = Vs + kvb * 4;
      bf16x4 w0 = {a0.x, a1.x, a2.x, a3.x};
      bf16x4 w1 = {a0.y, a1.y, a2.y, a3.y};
      bf16x4 w2 = {a0.z, a1.z, a2.z, a3.z};
      bf16x4 w3 = {a0.w, a1.w, a2.w, a3.w};
      *(bf16x4*)(db + (dv * 4 + 0) * 40) = w0;
      *(bf16x4*)(db + (dv * 4 + 1) * 40) = w1;
      *(bf16x4*)(db + (dv * 4 + 2) * 40) = w2;
      *(bf16x4*)(db + (dv * 4 + 3) * 40) = w3;
    }
    __syncthreads();
    f32x4 s0 = zf, s1 = zf;
    {
      bf16x8 k00 = *(const bf16x8*)(Ks + llo * 72 + lhi * 8);
      bf16x8 k01 = *(const bf16x8*)(Ks + llo * 72 + 32 + lhi * 8);
      bf16x8 k10 = *(const bf16x8*)(Ks + (16 + llo) * 72 + lhi * 8);
      bf16x8 k11 = *(const bf16x8*)(Ks + (16 + llo) * 72 + 32 + lhi * 8);
      s0 = mfma16(qfr[0], k00, s0);
      s0 = mfma16(qfr[1], k01, s0);
      s1 = mfma16(qfr[0], k10, s1);
      s1 = mfma16(qfr[1], k11, s1);
    }
    const int kvg = t * 32;
    const bool va = (kvg + llo) < NTOK;
    const bool vb2 = (kvg + 16 + llo) < NTOK;
    float p0[4], p1[4];
#pragma unroll
    for (int e = 0; e < 4; ++e) {
      p0[e] = va ? s0[e] * 0.125f : -1e30f;
      p1[e] = vb2 ? s1[e] * 0.125f : -1e30f;
    }
#pragma unroll
    for (int e = 0; e < 4; ++e) {
      float mx = fmaxf(p0[e], p1[e]);
#pragma unroll
      for (int d2 = 1; d2 < 16; d2 <<= 1) mx = fmaxf(mx, __shfl_xor(mx, d2));
      const float mn = fmaxf(mrun[e], mx);
      corr[e] = __expf(mrun[e] - mn);
      mrun[e] = mn;
      p0[e] = __expf(p0[e] - mn);
      p1[e] = __expf(p1[e] - mn);
      float ps = p0[e] + p1[e];
#pragma unroll
      for (int d2 = 1; d2 < 16; d2 <<= 1) ps += __shfl_xor(ps, d2);
      lrun[e] = lrun[e] * corr[e] + ps;
    }
    short* pw = Ps[w];
#pragma unroll
    for (int e = 0; e < 4; ++e) {
      pw[(lhi * 4 + e) * 40 + llo] = f2bf(p0[e]);
      pw[(lhi * 4 + e) * 40 + 16 + llo] = f2bf(p1[e]);
#pragma unroll
      for (int d = 0; d < 4; ++d) oacc[d][e] *= corr[e];
    }
    bf16x8 pa = *(const bf16x8*)(pw + llo * 40 + lhi * 8);
#pragma unroll
    for (int d = 0; d < 4; ++d) {
      bf16x8 vf = *(const bf16x8*)(Vs + (d * 16 + llo) * 40 + lhi * 8);
      oacc[d] = mfma16(pa, vf, oacc[d]);
    }
  }
#pragma unroll
  for (int d = 0; d < 4; ++d)
#pragma unroll
    for (int e = 0; e < 4; ++e) {
      const int n = q0 + lhi * 4 + e;
      if (n < NTOK)
        ob[((size_t)(b * NTOK + n)) * 768 + h * 64 + d * 16 + llo] =
            f2bf(oacc[d][e] / lrun[e]);
    }
}

extern "C" void kernel_launch(void* const* d_in, const int* in_sizes, int n_in,
                              void* d_out, int out_size, void* d_ws, size_t ws_size,
                              hipStream_t stream) {
  const float* x       = (const float*)d_in[0];
  const float* conv_w  = (const float*)d_in[1];
  const float* conv_b  = (const float*)d_in[2];
  const float* pos_emb = (const float*)d_in[3];
  const float* ln1_s   = (const float*)d_in[4];
  const float* ln1_b   = (const float*)d_in[5];
  const float* qkv_w   = (const float*)d_in[6];
  const float* qkv_b   = (const float*)d_in[7];
  const float* aow     = (const float*)d_in[8];
  const float* aob     = (const float*)d_in[9];
  const float* ln2_s   = (const float*)d_in[10];
  const float* ln2_b   = (const float*)d_in[11];
  const float* w1      = (const float*)d_in[12];
  const float* b1      = (const float*)d_in[13];
  const float* w2      = (const float*)d_in[14];
  const float* b2      = (const float*)d_in[15];
  const float* lnf_s   = (const float*)d_in[16];
  const float* lnf_b   = (const float*)d_in[17];
  (void)in_sizes; (void)n_in; (void)out_size; (void)ws_size;

  char* ws = (char*)d_ws;
  size_t off = 0;
  auto take = [&](size_t bytes) {
    char* p = ws + off;
    off += (bytes + 255) & ~(size_t)255;
    return p;
  };
  short* wq_t = (short*)take(12ull * 2304 * 768 * 2);
  short* wo_t = (short*)take(12ull * 768 * 768 * 2);
  short* w1_t = (short*)take(12ull * 3072 * 768 * 2);
  short* w2_t = (short*)take(12ull * 768 * 3072 * 2);
  short* wcc  = (short*)take(768ull * 4096 * 2);
  short* patches = (short*)take((size_t)MTOK * 4096 * 2);
  float* tok  = (float*)take((size_t)MTOK * 768 * 4);
  short* yb   = (short*)take((size_t)MTOK * 768 * 2);
  short* qbuf = (short*)take(24ull * NPAD * 64 * 2);
  short* kbuf = (short*)take(24ull * NPAD * 64 * 2);
  short* vbuf = (short*)take(24ull * NPAD * 64 * 2);
  short* obuf = (short*)take((size_t)MTOK * 768 * 2);
  short* hid  = (short*)take((size_t)MTOK * 3072 * 2);

  // weight prep
  transpose_cast_k<<<dim3(72, 24, 12), 256, 0, stream>>>(qkv_w, wq_t, 768, 2304);
  transpose_cast_k<<<dim3(24, 24, 12), 256, 0, stream>>>(aow, wo_t, 768, 768);
  transpose_cast_k<<<dim3(96, 24, 12), 256, 0, stream>>>(w1, w1_t, 768, 3072);
  transpose_cast_k<<<dim3(24, 96, 12), 256, 0, stream>>>(w2, w2_t, 3072, 768);
  cast_k<<<3072, 256, 0, stream>>>(conv_w, wcc, 768 * 4096 / 4);

  // patch embedding
  im2col_k<<<MTOK, 256, 0, stream>>>(x, patches);
  gemm_bt<EPI_CONV><<<dim3(20, 6), 256, 0, stream>>>(
      patches, wcc, conv_b, MTOK, 768, 4096, tok, pos_emb, nullptr, nullptr, nullptr);

  for (int i = 0; i < 12; ++i) {
    ln_k<true><<<MTOK, 256, 0, stream>>>(tok, ln1_s + i * 768, ln1_b + i * 768, yb, nullptr);
    gemm_bt<EPI_QKV><<<dim3(20, 18), 256, 0, stream>>>(
        yb, wq_t + (size_t)i * 2304 * 768, qkv_b + i * 2304, MTOK, 2304, 768,
        nullptr, nullptr, qbuf, kbuf, vbuf);
    attn_k<<<dim3(20, 24), 256, 0, stream>>>(qbuf, kbuf, vbuf, obuf);
    gemm_bt<EPI_ADDTOK><<<dim3(20, 6), 256, 0, stream>>>(
        obuf, wo_t + (size_t)i * 768 * 768, aob + i * 768, MTOK, 768, 768,
        tok, nullptr, nullptr, nullptr, nullptr);
    ln_k<true><<<MTOK, 256, 0, stream>>>(tok, ln2_s + i * 768, ln2_b + i * 768, yb, nullptr);
    gemm_bt<EPI_GELU><<<dim3(20, 24), 256, 0, stream>>>(
        yb, w1_t + (size_t)i * 3072 * 768, b1 + i * 3072, MTOK, 3072, 768,
        nullptr, nullptr, hid, nullptr, nullptr);
    gemm_bt<EPI_ADDTOK><<<dim3(20, 6), 256, 0, stream>>>(
        hid, w2_t + (size_t)i * 768 * 3072, b2 + i * 768, MTOK, 768, 3072,
        tok, nullptr, nullptr, nullptr, nullptr);
  }
  ln_k<false><<<MTOK, 256, 0, stream>>>(tok, lnf_s, lnf_b, nullptr, (float*)d_out);
}

// Round 3
// 2722.295 us; speedup vs baseline: 1.3225x; 1.3225x over previous
//
#include <hip/hip_runtime.h>

// ViT forward on MI355X. R1: split-K GEMMs (fp32 partials) + fused
// reduce/epilogue kernels (bias/GELU/scatter/residual + following LayerNorm).
// Per-layer weight transpose-cast to keep workspace small.

#define MTOK 2464
#define NTOK 1232
#define NPAD 1248

typedef __attribute__((ext_vector_type(8))) short bf16x8;
typedef __attribute__((ext_vector_type(4))) short bf16x4;
typedef __attribute__((ext_vector_type(4))) float f32x4;

__device__ __forceinline__ short f2bf(float f) {
  union { float f; unsigned u; } v; v.f = f;
  unsigned r = v.u + 0x7FFFu + ((v.u >> 16) & 1u);
  return (short)(r >> 16);
}

__device__ __forceinline__ f32x4 mfma16(bf16x8 a, bf16x8 b, f32x4 c) {
  return __builtin_amdgcn_mfma_f32_16x16x32_bf16(a, b, c, 0, 0, 0);
}

// ---- weight transpose-cast: src fp32 [R][C] -> dst bf16 [C][R]
__global__ __launch_bounds__(256)
void transpose_cast_k(const float* __restrict__ src, short* __restrict__ dst,
                      int R, int C) {
  __shared__ float t[32][33];
  const int tid = threadIdx.x;
  const int c0 = blockIdx.x * 32, r0 = blockIdx.y * 32;
  const int cc = tid & 31, rr = tid >> 5;
#pragma unroll
  for (int p = 0; p < 4; ++p)
    t[rr + p * 8][cc] = src[(size_t)(r0 + rr + p * 8) * C + c0 + cc];
  __syncthreads();
#pragma unroll
  for (int p = 0; p < 4; ++p)
    dst[(size_t)(c0 + rr + p * 8) * R + r0 + cc] = f2bf(t[cc][rr + p * 8]);
}

// ---- plain cast (conv_w already [N][K]-major)
__global__ __launch_bounds__(256)
void cast_k(const float* __restrict__ src, short* __restrict__ dst, int n4) {
  int i = blockIdx.x * 256 + threadIdx.x;
  if (i >= n4) return;
  float4 f = ((const float4*)src)[i];
  bf16x4 o; o.x = f2bf(f.x); o.y = f2bf(f.y); o.z = f2bf(f.z); o.w = f2bf(f.w);
  ((bf16x4*)dst)[i] = o;
}

// ---- im2col: x fp32 [2][1][112][256][176] -> patches bf16 [2464][4096]
__global__ __launch_bounds__(256)
void im2col_k(const float* __restrict__ x, short* __restrict__ patches) {
  const int row = blockIdx.x;
  const int tid = threadIdx.x;
  const int b = row >= NTOK;
  const int n = row - b * NTOK;
  const int dz = n / 176;
  const int r2 = n - dz * 176;
  const int dy = r2 / 11;
  const int dx = r2 - dy * 11;
  const int pz = tid >> 4, py = tid & 15;
  const float* src = x + (((size_t)(b * 112 + dz * 16 + pz) * 256) + dy * 16 + py) * 176 + dx * 16;
  short* dst = patches + (size_t)row * 4096 + pz * 256 + py * 16;
#pragma unroll
  for (int q = 0; q < 4; ++q) {
    float4 f = ((const float4*)src)[q];
    bf16x4 o; o.x = f2bf(f.x); o.y = f2bf(f.y); o.z = f2bf(f.z); o.w = f2bf(f.w);
    ((bf16x4*)dst)[q] = o;
  }
}

// ---- split-K GEMM: A bf16 [M][K], B bf16 [N][K]; 128x128x32 tile;
//      writes fp32 partials part[s][M][N], s = blockIdx.z.
template<int SPLIT>
__global__ __launch_bounds__(256, 4)
void gemm_ps(const short* __restrict__ A, const short* __restrict__ B,
             float* __restrict__ part, int M, int N, int K) {
  __shared__ short As[128 * 32];
  __shared__ short Bs[128 * 32];
  const int tid = threadIdx.x;
  const int l = tid & 63, w = tid >> 6;
  const int lhi = l >> 4, llo = l & 15;
  const int wr = w >> 1, wc = w & 1;
  const int m0 = blockIdx.x * 128, n0 = blockIdx.y * 128;
  const int s = blockIdx.z;
  const int Ks = K / SPLIT, kbeg = s * Ks;

  const f32x4 zf = {0.f, 0.f, 0.f, 0.f};
  f32x4 acc[4][4];
#pragma unroll
  for (int r = 0; r < 4; ++r)
#pragma unroll
    for (int c = 0; c < 4; ++c) acc[r][c] = zf;

  for (int k0 = kbeg; k0 < kbeg + Ks; k0 += 32) {
#pragma unroll
    for (int p = 0; p < 2; ++p) {
      const int f = p * 256 + tid;
      const int row = f >> 2, kc = f & 3;
      int gr = m0 + row; gr = gr < M ? gr : M - 1;
      const short* gp = A + (size_t)gr * K + k0 + kc * 8;
      __builtin_amdgcn_global_load_lds(
          (const __attribute__((address_space(1))) unsigned*)gp,
          (__attribute__((address_space(3))) unsigned*)(As + (p * 256 + w * 64) * 8),
          16, 0, 0);
    }
#pragma unroll
    for (int p = 0; p < 2; ++p) {
      const int f = p * 256 + tid;
      const int row = f >> 2, kc = f & 3;
      const short* gp = B + (size_t)(n0 + row) * K + k0 + kc * 8;
      __builtin_amdgcn_global_load_lds(
          (const __attribute__((address_space(1))) unsigned*)gp,
          (__attribute__((address_space(3))) unsigned*)(Bs + (p * 256 + w * 64) * 8),
          16, 0, 0);
    }
    __syncthreads();
    bf16x8 af[4], bfr[4];
#pragma unroll
    for (int r = 0; r < 4; ++r)
      af[r] = *(const bf16x8*)(As + (wr * 64 + r * 16 + llo) * 32 + lhi * 8);
#pragma unroll
    for (int c = 0; c < 4; ++c)
      bfr[c] = *(const bf16x8*)(Bs + (wc * 64 + c * 16 + llo) * 32 + lhi * 8);
#pragma unroll
    for (int r = 0; r < 4; ++r)
#pragma unroll
      for (int c = 0; c < 4; ++c)
        acc[r][c] = mfma16(af[r], bfr[c], acc[r][c]);
    __syncthreads();
  }

  float* pp = part + (size_t)s * M * N;
#pragma unroll
  for (int c = 0; c < 4; ++c) {
    const int gcol = n0 + wc * 64 + c * 16 + llo;
#pragma unroll
    for (int r = 0; r < 4; ++r) {
      const int rb = m0 + wr * 64 + r * 16 + lhi * 4;
#pragma unroll
      for (int e = 0; e < 4; ++e) {
        const int grow = rb + e;
        if (grow < M) pp[(size_t)grow * N + gcol] = acc[r][c][e];
      }
    }
  }
}

// ---- reduce partials (S=2) + bias, scatter q/k/v to [B,H,NPAD,64] bf16
__global__ __launch_bounds__(256)
void reduce_qkv_k(const float* __restrict__ part, const float* __restrict__ bias,
                  short* __restrict__ qb, short* __restrict__ kb,
                  short* __restrict__ vb) {
  const int idx = blockIdx.x * 256 + threadIdx.x;  // < 2464*576
  const int row = idx / 576;
  const int c4 = (idx - row * 576) * 4;
  const float4 p0 = *(const float4*)(part + ((size_t)0 * MTOK + row) * 2304 + c4);
  const float4 p1 = *(const float4*)(part + ((size_t)1 * MTOK + row) * 2304 + c4);
  const float4 bv = *(const float4*)(bias + c4);
  const int which = c4 / 768, hc = c4 - which * 768;
  const int b = row >= NTOK, n = row - b * NTOK;
  short* dst = which == 0 ? qb : (which == 1 ? kb : vb);
  bf16x4 o;
  o.x = f2bf(p0.x + p1.x + bv.x);
  o.y = f2bf(p0.y + p1.y + bv.y);
  o.z = f2bf(p0.z + p1.z + bv.z);
  o.w = f2bf(p0.w + p1.w + bv.w);
  *(bf16x4*)(dst + ((size_t)(b * 12 + (hc >> 6)) * NPAD + n) * 64 + (hc & 63)) = o;
}

// ---- reduce partials (S=2) + bias + exact GELU -> hid bf16 [M][3072]
__global__ __launch_bounds__(256)
void reduce_gelu_k(const float* __restrict__ part, const float* __restrict__ bias,
                   short* __restrict__ hid) {
  const int idx = blockIdx.x * 256 + threadIdx.x;  // < 2464*768
  const int row = idx / 768;
  const int c4 = (idx - row * 768) * 4;
  const float4 p0 = *(const float4*)(part + ((size_t)0 * MTOK + row) * 3072 + c4);
  const float4 p1 = *(const float4*)(part + ((size_t)1 * MTOK + row) * 3072 + c4);
  const float4 bv = *(const float4*)(bias + c4);
  float v[4] = {p0.x + p1.x + bv.x, p0.y + p1.y + bv.y,
                p0.z + p1.z + bv.z, p0.w + p1.w + bv.w};
  bf16x4 o;
#pragma unroll
  for (int i = 0; i < 4; ++i) {
    const float g = 0.5f * v[i] * (1.f + erff(v[i] * 0.70710678118f));
    ((short*)&o)[i] = f2bf(g);
  }
  *(bf16x4*)(hid + (size_t)row * 3072 + c4) = o;
}

// ---- reduce partials (S) + bias (+pos | +tok residual) -> tok, then LN -> yb/yf
template<int S, bool ADDPOS, bool BF16OUT>
__global__ __launch_bounds__(256)
void reduce_rowln_k(const float* __restrict__ part, const float* __restrict__ bias,
                    const float* __restrict__ pos, float* __restrict__ tok,
                    const float* __restrict__ sc, const float* __restrict__ bi,
                    short* __restrict__ yb, float* __restrict__ yf) {
  const int row = blockIdx.x, tid = threadIdx.x;
  float v[3];
#pragma unroll
  for (int i = 0; i < 3; ++i) {
    const int c = tid + i * 256;
    float a = bias[c];
#pragma unroll
    for (int s = 0; s < S; ++s)
      a += part[((size_t)s * MTOK + row) * 768 + c];
    if (ADDPOS) {
      const int n = row - (row >= NTOK ? NTOK : 0);
      a += pos[(size_t)n * 768 + c];
    } else {
      a += tok[(size_t)row * 768 + c];
    }
    tok[(size_t)row * 768 + c] = a;
    v[i] = a;
  }
  float s1 = v[0] + v[1] + v[2];
  float s2 = v[0] * v[0] + v[1] * v[1] + v[2] * v[2];
#pragma unroll
  for (int d = 1; d < 64; d <<= 1) { s1 += __shfl_xor(s1, d); s2 += __shfl_xor(s2, d); }
  __shared__ float sh[8];
  const int w = tid >> 6;
  if ((tid & 63) == 0) { sh[w] = s1; sh[4 + w] = s2; }
  __syncthreads();
  s1 = sh[0] + sh[1] + sh[2] + sh[3];
  s2 = sh[4] + sh[5] + sh[6] + sh[7];
  const float mean = s1 * (1.f / 768.f);
  const float var = s2 * (1.f / 768.f) - mean * mean;
  const float rs = rsqrtf(var + 1e-5f);
#pragma unroll
  for (int i = 0; i < 3; ++i) {
    const int c = tid + i * 256;
    const float o = (v[i] - mean) * rs * sc[c] + bi[c];
    if (BF16OUT) yb[(size_t)row * 768 + c] = f2bf(o);
    else         yf[(size_t)row * 768 + c] = o;
  }
}

// ---- fused flash attention: grid (20 qtiles, 24 bh); 4 waves x 16 q-rows.
__global__ __launch_bounds__(256, 3)
void attn_k(const short* __restrict__ qb, const short* __restrict__ kb,
            const short* __restrict__ vb, short* __restrict__ ob) {
  const int tid = threadIdx.x;
  const int l = tid & 63, w = tid >> 6;
  const int lhi = l >> 4, llo = l & 15;
  const int qt = blockIdx.x, bh = blockIdx.y;
  const int b = bh / 12, h = bh - b * 12;
  const size_t base = (size_t)bh * NPAD * 64;
  const short* qp = qb + base;
  const short* kp = kb + base;
  const short* vp = vb + base;

  __shared__ short Ks[32 * 72];
  __shared__ short Vs[64 * 40];
  __shared__ short Ps[4][16 * 40];

  const int q0 = qt * 64 + w * 16;
  bf16x8 qfr[2];
  {
    int r = q0 + llo; if (r > NTOK - 1) r = NTOK - 1;
    qfr[0] = *(const bf16x8*)(qp + (size_t)r * 64 + lhi * 8);
    qfr[1] = *(const bf16x8*)(qp + (size_t)r * 64 + 32 + lhi * 8);
  }
  const f32x4 zf = {0.f, 0.f, 0.f, 0.f};
  float mrun[4], lrun[4], corr[4];
  f32x4 oacc[4];
#pragma unroll
  for (int e = 0; e < 4; ++e) { mrun[e] = -1e30f; lrun[e] = 0.f; }
#pragma unroll
  for (int d = 0; d < 4; ++d) oacc[d] = zf;

  for (int t = 0; t < 39; ++t) {
    __syncthreads();
    if (tid < 128) {
      const int kvr = tid >> 2, dc2 = tid & 3;
      const short* sp = kp + (size_t)(t * 32 + kvr) * 64 + dc2 * 16;
      *(bf16x8*)(Ks + kvr * 72 + dc2 * 16) = *(const bf16x8*)sp;
      *(bf16x8*)(Ks + kvr * 72 + dc2 * 16 + 8) = *(const bf16x8*)(sp + 8);
    } else {
      const int t2 = tid - 128;
      const int dv = t2 & 15, kvb = t2 >> 4;
      const short* sp = vp + (size_t)(t * 32 + kvb * 4) * 64 + dv * 4;
      bf16x4 a0 = *(const bf16x4*)(sp);
      bf16x4 a1 = *(const bf16x4*)(sp + 64);
      bf16x4 a2 = *(const bf16x4*)(sp + 128);
      bf16x4 a3 = *(const bf16x4*)(sp + 192);
      short* db = Vs + kvb * 4;
      bf16x4 w0 = {a0.x, a1.x, a2.x, a3.x};
      bf16x4 w1 = {a0.y, a1.y, a2.y, a3.y};
      bf16x4 w2 = {a0.z, a1.z, a2.z, a3.z};
      bf16x4 w3 = {a0.w, a1.w, a2.w, a3.w};
      *(bf16x4*)(db + (dv * 4 + 0) * 40) = w0;
      *(bf16x4*)(db + (dv * 4 + 1) * 40) = w1;
      *(bf16x4*)(db + (dv * 4 + 2) * 40) = w2;
      *(bf16x4*)(db + (dv * 4 + 3) * 40) = w3;
    }
    __syncthreads();
    f32x4 s0 = zf, s1 = zf;
    {
      bf16x8 k00 = *(const bf16x8*)(Ks + llo * 72 + lhi * 8);
      bf16x8 k01 = *(const bf16x8*)(Ks + llo * 72 + 32 + lhi * 8);
      bf16x8 k10 = *(const bf16x8*)(Ks + (16 + llo) * 72 + lhi * 8);
      bf16x8 k11 = *(const bf16x8*)(Ks + (16 + llo) * 72 + 32 + lhi * 8);
      s0 = mfma16(qfr[0], k00, s0);
      s0 = mfma16(qfr[1], k01, s0);
      s1 = mfma16(qfr[0], k10, s1);
      s1 = mfma16(qfr[1], k11, s1);
    }
    const int kvg = t * 32;
    const bool va = (kvg + llo) < NTOK;
    const bool vb2 = (kvg + 16 + llo) < NTOK;
    float p0[4], p1[4];
#pragma unroll
    for (int e = 0; e < 4; ++e) {
      p0[e] = va ? s0[e] * 0.125f : -1e30f;
      p1[e] = vb2 ? s1[e] * 0.125f : -1e30f;
    }
#pragma unroll
    for (int e = 0; e < 4; ++e) {
      float mx = fmaxf(p0[e], p1[e]);
#pragma unroll
      for (int d2 = 1; d2 < 16; d2 <<= 1) mx = fmaxf(mx, __shfl_xor(mx, d2));
      const float mn = fmaxf(mrun[e], mx);
      corr[e] = __expf(mrun[e] - mn);
      mrun[e] = mn;
      p0[e] = __expf(p0[e] - mn);
      p1[e] = __expf(p1[e] - mn);
      float ps = p0[e] + p1[e];
#pragma unroll
      for (int d2 = 1; d2 < 16; d2 <<= 1) ps += __shfl_xor(ps, d2);
      lrun[e] = lrun[e] * corr[e] + ps;
    }
    short* pw = Ps[w];
#pragma unroll
    for (int e = 0; e < 4; ++e) {
      pw[(lhi * 4 + e) * 40 + llo] = f2bf(p0[e]);
      pw[(lhi * 4 + e) * 40 + 16 + llo] = f2bf(p1[e]);
#pragma unroll
      for (int d = 0; d < 4; ++d) oacc[d][e] *= corr[e];
    }
    bf16x8 pa = *(const bf16x8*)(pw + llo * 40 + lhi * 8);
#pragma unroll
    for (int d = 0; d < 4; ++d) {
      bf16x8 vf = *(const bf16x8*)(Vs + (d * 16 + llo) * 40 + lhi * 8);
      oacc[d] = mfma16(pa, vf, oacc[d]);
    }
  }
#pragma unroll
  for (int d = 0; d < 4; ++d)
#pragma unroll
    for (int e = 0; e < 4; ++e) {
      const int n = q0 + lhi * 4 + e;
      if (n < NTOK)
        ob[((size_t)(b * NTOK + n)) * 768 + h * 64 + d * 16 + llo] =
            f2bf(oacc[d][e] / lrun[e]);
    }
}

extern "C" void kernel_launch(void* const* d_in, const int* in_sizes, int n_in,
                              void* d_out, int out_size, void* d_ws, size_t ws_size,
                              hipStream_t stream) {
  const float* x       = (const float*)d_in[0];
  const float* conv_w  = (const float*)d_in[1];
  const float* conv_b  = (const float*)d_in[2];
  const float* pos_emb = (const float*)d_in[3];
  const float* ln1_s   = (const float*)d_in[4];
  const float* ln1_b   = (const float*)d_in[5];
  const float* qkv_w   = (const float*)d_in[6];
  const float* qkv_b   = (const float*)d_in[7];
  const float* aow     = (const float*)d_in[8];
  const float* aob     = (const float*)d_in[9];
  const float* ln2_s   = (const float*)d_in[10];
  const float* ln2_b   = (const float*)d_in[11];
  const float* w1      = (const float*)d_in[12];
  const float* b1      = (const float*)d_in[13];
  const float* w2      = (const float*)d_in[14];
  const float* b2      = (const float*)d_in[15];
  const float* lnf_s   = (const float*)d_in[16];
  const float* lnf_b   = (const float*)d_in[17];
  (void)in_sizes; (void)n_in; (void)out_size; (void)ws_size;

  char* ws = (char*)d_ws;
  size_t off = 0;
  auto take = [&](size_t bytes) {
    char* p = ws + off;
    off += (bytes + 255) & ~(size_t)255;
    return p;
  };
  short* wq_t = (short*)take(2304ull * 768 * 2);   // per-layer
  short* wo_t = (short*)take(768ull * 768 * 2);
  short* w1_t = (short*)take(3072ull * 768 * 2);
  short* w2_t = (short*)take(768ull * 3072 * 2);
  short* wcc  = (short*)take(768ull * 4096 * 2);
  short* patches = (short*)take((size_t)MTOK * 4096 * 2);
  float* tok  = (float*)take((size_t)MTOK * 768 * 4);
  short* yb   = (short*)take((size_t)MTOK * 768 * 2);
  short* qbuf = (short*)take(24ull * NPAD * 64 * 2);
  short* kbuf = (short*)take(24ull * NPAD * 64 * 2);
  short* vbuf = (short*)take(24ull * NPAD * 64 * 2);
  short* obuf = (short*)take((size_t)MTOK * 768 * 2);
  short* hid  = (short*)take((size_t)MTOK * 3072 * 2);
  float* part = (float*)take(2ull * MTOK * 3072 * 4);  // 60.5 MB, max partial

  // patch embedding
  cast_k<<<3072, 256, 0, stream>>>(conv_w, wcc, 768 * 4096 / 4);
  im2col_k<<<MTOK, 256, 0, stream>>>(x, patches);
  gemm_ps<4><<<dim3(20, 6, 4), 256, 0, stream>>>(patches, wcc, part, MTOK, 768, 4096);
  reduce_rowln_k<4, true, true><<<MTOK, 256, 0, stream>>>(
      part, conv_b, pos_emb, tok, ln1_s, ln1_b, yb, nullptr);

  for (int i = 0; i < 12; ++i) {
    transpose_cast_k<<<dim3(72, 24), 256, 0, stream>>>(qkv_w + (size_t)i * 768 * 2304, wq_t, 768, 2304);
    transpose_cast_k<<<dim3(24, 24), 256, 0, stream>>>(aow + (size_t)i * 768 * 768, wo_t, 768, 768);
    transpose_cast_k<<<dim3(96, 24), 256, 0, stream>>>(w1 + (size_t)i * 768 * 3072, w1_t, 768, 3072);
    transpose_cast_k<<<dim3(24, 96), 256, 0, stream>>>(w2 + (size_t)i * 3072 * 768, w2_t, 3072, 768);

    gemm_ps<2><<<dim3(20, 18, 2), 256, 0, stream>>>(yb, wq_t, part, MTOK, 2304, 768);
    reduce_qkv_k<<<5544, 256, 0, stream>>>(part, qkv_b + i * 2304, qbuf, kbuf, vbuf);
    attn_k<<<dim3(20, 24), 256, 0, stream>>>(qbuf, kbuf, vbuf, obuf);
    gemm_ps<4><<<dim3(20, 6, 4), 256, 0, stream>>>(obuf, wo_t, part, MTOK, 768, 768);
    reduce_rowln_k<4, false, true><<<MTOK, 256, 0, stream>>>(
        part, aob + i * 768, nullptr, tok, ln2_s + i * 768, ln2_b + i * 768, yb, nullptr);
    gemm_ps<2><<<dim3(20, 24, 2), 256, 0, stream>>>(yb, w1_t, part, MTOK, 3072, 768);
    reduce_gelu_k<<<7392, 256, 0, stream>>>(part, b1 + i * 3072, hid);
    gemm_ps<4><<<dim3(20, 6, 4), 256, 0, stream>>>(hid, w2_t, part, MTOK, 768, 3072);
    if (i < 11) {
      reduce_rowln_k<4, false, true><<<MTOK, 256, 0, stream>>>(
          part, b2 + i * 768, nullptr, tok, ln1_s + (i + 1) * 768, ln1_b + (i + 1) * 768, yb, nullptr);
    } else {
      reduce_rowln_k<4, false, false><<<MTOK, 256, 0, stream>>>(
          part, b2 + i * 768, nullptr, tok, lnf_s, lnf_b, nullptr, (float*)d_out);
    }
  }
}